// Round 1
// baseline (64.838 us; speedup 1.0000x reference)
//
#include <hip/hip_runtime.h>
#include <stdint.h>

// CandidateFinder: binary-quantize (x>0), exact match on two 32-bit dim
// groups (union), gather first <=64 matching key indices per query, pad -1.
//
// R11 -> R12: floor is the harness's ~41us 268MB poison fill (82% HBM peak,
// rocprof); controllable budget ~16us = sig + match + 2 launches. match's
// scan was LDS-pipe bound: 2 q/wave x separate passes = 32 ds_read_b128/wave
// (6144 cyc/CU). Now 4 q/wave, ONE pass: 16 reads/wave serve 8 key-tests
// each (1536 cyc/CU, 4x less LDS traffic). Hot loop drops ballot+popcll
// bookkeeping: query sigs are SGPRs (ballot results), match detect is
// v_cmp_eq -> s_or (SALU, parallel pipe); exact count is recomputed only in
// the rare (p~2^-26/wave) ordered-emit slow path, which padding reuses.
//
// wave=64 lanes <-> 64 dims: __ballot(v>0) IS the row's two 32-bit group
// signatures in canonical bit order. Matches emitted in ascending key order
// via ballot+popcount prefix = reference's sort-then-truncate.

#define LSEQ 2048
#define DDIM 64
#define KMAX 64
#define RPW  8    // rows packed per wave in sig kernel
#define MQPB 32   // queries per match block (512 thr, 8 waves, 4 q/wave)
#define QPW  4    // queries per wave in match kernel

// Phase 1: pack key sign bits (R6's proven kernel, unchanged).
__global__ __launch_bounds__(256) void sig_kernel(
    const float* __restrict__ key, uint2* __restrict__ ksig, int nrows) {
    int wid  = (int)((blockIdx.x * blockDim.x + threadIdx.x) >> 6);
    int lane = threadIdx.x & 63;
    int row0 = wid * RPW;
    if (row0 >= nrows) return;                      // wave-uniform
    const float* base = key + (size_t)row0 * DDIM + lane;
    float v[RPW];
#pragma unroll
    for (int u = 0; u < RPW; ++u)                   // 8 loads, one BB
        v[u] = base[(size_t)u * DDIM];              // 256B/wave coalesced
    unsigned long long m[RPW];
#pragma unroll
    for (int u = 0; u < RPW; ++u)
        m[u] = __ballot(v[u] > 0.0f);               // branchless, scalar dst
    if (lane == 0) {                                // one exec toggle
#pragma unroll
        for (int u = 0; u < RPW; ++u)               // 64B contiguous
            ksig[row0 + u] = make_uint2((unsigned)m[u], (unsigned)(m[u] >> 32));
    }
}

// Phase 2: 256 blocks x 512 thr; block stages its batch's 16KB sig table in
// LDS (two uint4 per thread), then 8 waves scan 4 queries each in ONE pass.
__global__ __launch_bounds__(512) void match_kernel(
    const float* __restrict__ query, const uint2* __restrict__ ksig,
    int* __restrict__ out) {
    __shared__ uint4 sh[LSEQ / 2];      // 16 KB (uint4 = 2 key sigs)

    const int bpb = LSEQ / MQPB;        // 64 blocks per batch
    int b    = blockIdx.x / bpb;
    int qblk = blockIdx.x % bpb;
    int lane = threadIdx.x & 63;
    int wave = threadIdx.x >> 6;        // 0..7

    // stage: 512 threads x 2 x 16B = whole table, one global round-trip
    const uint4* gt = (const uint4*)(ksig + (size_t)b * LSEQ);
    sh[threadIdx.x]       = gt[threadIdx.x];
    sh[threadIdx.x + 512] = gt[threadIdx.x + 512];

    // this wave's 4 query signatures (overlap with staging latency);
    // ballot results are wave-uniform -> live in SGPRs, not VGPRs
    int q0 = b * LSEQ + qblk * MQPB + wave * QPW;   // global query idx
    const float* qp = query + (size_t)q0 * DDIM + lane;
    unsigned qa[QPW], qg[QPW];
#pragma unroll
    for (int t = 0; t < QPW; ++t) {
        unsigned long long qm = __ballot(qp[(size_t)t * DDIM] > 0.0f);
        qa[t] = (unsigned)qm;
        qg[t] = (unsigned)(qm >> 32);
    }

    __syncthreads();

    // fast path: one pass, 16 ds_read_b128, each serving 4 queries x 2 keys.
    // Per iter per query: 4 v_cmp_eq (1 SGPR operand each, legal) + s_or
    // chain on the SALU pipe. No popcounts, no per-iter cnt.
    unsigned long long acc[QPW] = {};
#pragma unroll
    for (int i = 0; i < LSEQ / 128; ++i) {          // 16 iters, 128 keys
        uint4 kv = sh[i * 64 + lane];
#pragma unroll
        for (int t = 0; t < QPW; ++t) {
            unsigned long long sA = __ballot(kv.x == qa[t]);  // key 2*(i*64+lane)
            unsigned long long sG = __ballot(kv.y == qg[t]);
            unsigned long long sB = __ballot(kv.z == qa[t]);  // key 2*(i*64+lane)+1
            unsigned long long sH = __ballot(kv.w == qg[t]);
            acc[t] |= sA | sG | sB | sH;            // "any match" detector
        }
    }

    unsigned long long below = (1ull << lane) - 1ull;
    const uint2* ks2 = (const uint2*)sh;
#pragma unroll
    for (int t = 0; t < QPW; ++t) {
        int* ob = out + (size_t)(q0 + t) * KMAX;
        int cnt = 0;
        if (acc[t] != 0) {                          // wave-uniform, p~2^-26:
            // exact ordered emit (ascending key idx = sort-then-truncate)
            for (int c = 0; c < LSEQ / 64; ++c) {
                uint2 kv = ks2[c * 64 + lane];
                bool m = (kv.x == qa[t]) || (kv.y == qg[t]);
                unsigned long long mask = __ballot(m);
                if (m) {
                    int pos = cnt + __popcll(mask & below);
                    if (pos < KMAX) ob[pos] = c * 64 + lane;
                }
                cnt += __popcll(mask);
            }
        }
        // pad remaining slots with -1 (64 lanes == KMAX; disjoint vs matches)
        if (lane >= cnt) ob[lane] = -1;
    }
}

// Fallback (ws too small): R5's proven self-contained fused kernel.
#define QPB  32
#define NW   16
#define GROUP 32
__global__ __launch_bounds__(1024) void fused_kernel(
    const float* __restrict__ query, const float* __restrict__ key,
    int* __restrict__ out) {
    __shared__ uint2 ks[LSEQ];
    const int bpb  = LSEQ / QPB;
    int b    = blockIdx.x / bpb;
    int qblk = blockIdx.x % bpb;
    int lane = threadIdx.x & 63;
    int wave = threadIdx.x >> 6;
    const float* kb = key + (size_t)b * LSEQ * DDIM;
    for (int g = 0; g < LSEQ / NW / GROUP; ++g) {
        float v[GROUP];
#pragma unroll
        for (int u = 0; u < GROUP; ++u)
            v[u] = kb[(size_t)(g * (NW * GROUP) + u * NW + wave) * DDIM + lane];
        unsigned long long m[GROUP];
#pragma unroll
        for (int u = 0; u < GROUP; ++u) m[u] = __ballot(v[u] > 0.0f);
        if (lane == 0) {
#pragma unroll
            for (int u = 0; u < GROUP; ++u)
                ks[g * (NW * GROUP) + u * NW + wave] =
                    make_uint2((unsigned)m[u], (unsigned)(m[u] >> 32));
        }
    }
    const float* qb = query + ((size_t)b * LSEQ + (size_t)qblk * QPB) * DDIM;
    int q0 = wave * 2;
    float v0 = qb[(size_t)q0 * DDIM + lane];
    float v1 = qb[(size_t)(q0 + 1) * DDIM + lane];
    unsigned long long m0 = __ballot(v0 > 0.0f);
    unsigned long long m1 = __ballot(v1 > 0.0f);
    __syncthreads();
    unsigned long long below = (1ull << lane) - 1ull;
    for (int t = 0; t < 2; ++t) {
        unsigned long long qm = t ? m1 : m0;
        unsigned q1 = (unsigned)qm, q2 = (unsigned)(qm >> 32);
        int* obase = out + ((size_t)b * LSEQ + (size_t)qblk * QPB + q0 + t) * KMAX;
        unsigned long long acc = 0;
        int cnt = 0;
#pragma unroll
        for (int c = 0; c < LSEQ / 64; ++c) {
            uint2 kv = ks[c * 64 + lane];
            bool m = (kv.x == q1) || (kv.y == q2);
            unsigned long long mask = __ballot(m);
            acc |= mask; cnt += __popcll(mask);
        }
        if (acc != 0) {
            int c2 = 0;
            for (int c = 0; c < LSEQ / 64; ++c) {
                uint2 kv = ks[c * 64 + lane];
                bool m = (kv.x == q1) || (kv.y == q2);
                unsigned long long mask = __ballot(m);
                if (m) {
                    int pos = c2 + __popcll(mask & below);
                    if (pos < KMAX) obase[pos] = c * 64 + lane;
                }
                c2 += __popcll(mask);
            }
        }
        if (lane >= cnt) obase[lane] = -1;
    }
}

extern "C" void kernel_launch(void* const* d_in, const int* in_sizes, int n_in,
                              void* d_out, int out_size, void* d_ws, size_t ws_size,
                              hipStream_t stream) {
    const float* q = (const float*)d_in[0];
    const float* k = (const float*)d_in[1];
    // d_in[2] = head_idx, unused (inputs are already per-head)
    int* out = (int*)d_out;

    int total = in_sizes[0];             // B * L * D
    int B = total / (LSEQ * DDIM);       // = 4
    int nrows = B * LSEQ;                // 8192

    if (ws_size >= (size_t)nrows * sizeof(uint2)) {
        uint2* ksig = (uint2*)d_ws;
        sig_kernel<<<nrows / RPW * 64 / 256, 256, 0, stream>>>(k, ksig, nrows);
        match_kernel<<<nrows / MQPB, 512, 0, stream>>>(q, ksig, out);
    } else {
        fused_kernel<<<B * (LSEQ / QPB), 1024, 0, stream>>>(q, k, out);
    }
}